// Round 5
// baseline (583.934 us; speedup 1.0000x reference)
//
#include <hip/hip_runtime.h>

// ---- problem constants ----
#define SEQ     2048
#define HIDDEN  4544          // 71 * 64
#define NHEAD   71
#define HD      64
#define QKV_OUT 4672          // (71+2)*64
#define KSPLIT  2304          // 36*64; second half 2240 = 35*64

typedef __bf16    bf16;
typedef _Float16  f16;
typedef __bf16    bf16x8 __attribute__((ext_vector_type(8)));
typedef __bf16    bf16x4 __attribute__((ext_vector_type(4)));
typedef _Float16  f16x4  __attribute__((ext_vector_type(4)));
typedef float     f32x4  __attribute__((ext_vector_type(4)));

// async global->LDS, 16B per lane. ldsbase must be wave-uniform; HW adds lane*16B.
__device__ inline void gl2lds16(const void* g, void* ldsbase) {
  __builtin_amdgcn_global_load_lds(
      (const __attribute__((address_space(1))) unsigned int*)g,
      (__attribute__((address_space(3))) unsigned int*)ldsbase,
      16, 0, 0);
}

// ---------------- fp32 -> bf16 convert (vectorized) ----------------
__global__ void cvt_f32_bf16_k(const float* __restrict__ in, bf16* __restrict__ out, int n4) {
  int i = blockIdx.x * blockDim.x + threadIdx.x;
  if (i >= n4) return;
  float4 f = ((const float4*)in)[i];
  bf16x4 o;
  o[0] = (bf16)f.x; o[1] = (bf16)f.y; o[2] = (bf16)f.z; o[3] = (bf16)f.w;
  *(bf16x4*)(out + (size_t)i * 4) = o;
}

// ---------------- cos/sin tables for RoPE ----------------
__global__ __launch_bounds__(64) void tab_k(float* __restrict__ cs_tab,
                                            float* __restrict__ sn_tab) {
  const int s = blockIdx.x, t = threadIdx.x;
  const int i = t & 31;
  double invf = pow(10000.0, -(double)i / 32.0);
  double ang = (double)s * invf;
  cs_tab[s * 64 + t] = (float)cos(ang);
  sn_tab[s * 64 + t] = (float)sin(ang);
}

// ---------------- split-K bt-GEMM, BK=64: Cp[z] = A[:, krange_z] * B[:, krange_z]^T ----------------
// 128x128 C-tile, 256 threads (4 waves, 2x2 of 64x64). blockIdx.z picks the K-half;
// doubles grid occupancy (2.3 -> 4.6 blocks/CU) to hide the barrier vmcnt drains.
// Partials stored bf16 (quantization ~6e-5 << 2.2e-3 threshold).
__global__ __launch_bounds__(256) void gemm_bt_splitk(const bf16* __restrict__ A,
                                                      const bf16* __restrict__ B,
                                                      bf16* __restrict__ Cp,
                                                      int K, int Nmat, int ldc,
                                                      size_t partStride) {
  __shared__ bf16 lA[2][128 * 32];
  __shared__ bf16 lB[2][128 * 32];
  const int t = threadIdx.x;
  const int lane = t & 63, w = t >> 6;
  const int m0 = blockIdx.x * 128, n0 = blockIdx.y * 128;
  const int wm = (w >> 1) * 64, wn = (w & 1) * 64;
  const int qi = lane & 15, grp = lane >> 4;
  const int kbeg = blockIdx.z ? KSPLIT : 0;
  const int kend = blockIdx.z ? K : KSPLIT;

  const int r0 = t >> 2;
  const int c0 = (t & 3) * 8;
  const bf16* gA0 = A + (size_t)(m0 + r0) * K + c0;
  const bf16* gA1 = A + (size_t)(m0 + 64 + r0) * K + c0;
  int bR0 = n0 + r0;      if (bR0 >= Nmat) bR0 = Nmat - 1;
  int bR1 = n0 + 64 + r0; if (bR1 >= Nmat) bR1 = Nmat - 1;
  const bf16* gB0 = B + (size_t)bR0 * K + c0;
  const bf16* gB1 = B + (size_t)bR1 * K + c0;
  bf16* lA00 = &lA[0][0] + w * 512;
  bf16* lA01 = &lA[0][2048] + w * 512;
  bf16* lA10 = &lA[1][0] + w * 512;
  bf16* lA11 = &lA[1][2048] + w * 512;
  bf16* lB00 = &lB[0][0] + w * 512;
  bf16* lB01 = &lB[0][2048] + w * 512;
  bf16* lB10 = &lB[1][0] + w * 512;
  bf16* lB11 = &lB[1][2048] + w * 512;

  f32x4 acc[4][4] = {};
  for (int k0 = kbeg; k0 < kend; k0 += 64) {
    __syncthreads();
    gl2lds16(gA0 + k0,      lA00);
    gl2lds16(gA1 + k0,      lA01);
    gl2lds16(gA0 + k0 + 32, lA10);
    gl2lds16(gA1 + k0 + 32, lA11);
    gl2lds16(gB0 + k0,      lB00);
    gl2lds16(gB1 + k0,      lB01);
    gl2lds16(gB0 + k0 + 32, lB10);
    gl2lds16(gB1 + k0 + 32, lB11);
    __syncthreads();
#pragma unroll
    for (int half = 0; half < 2; ++half) {
      bf16x8 af[4], bfv[4];
#pragma unroll
      for (int i = 0; i < 4; ++i)
        af[i] = *(const bf16x8*)&lA[half][(wm + i * 16 + qi) * 32 + grp * 8];
#pragma unroll
      for (int i = 0; i < 4; ++i)
        bfv[i] = *(const bf16x8*)&lB[half][(wn + i * 16 + qi) * 32 + grp * 8];
#pragma unroll
      for (int i = 0; i < 4; ++i)
#pragma unroll
        for (int j = 0; j < 4; ++j)
          acc[i][j] = __builtin_amdgcn_mfma_f32_16x16x32_bf16(af[i], bfv[j], acc[i][j], 0, 0, 0);
    }
  }

  bf16* Cz = Cp + blockIdx.z * partStride;
#pragma unroll
  for (int i = 0; i < 4; ++i) {
    const int row = m0 + wm + i * 16 + grp * 4;
#pragma unroll
    for (int j = 0; j < 4; ++j) {
      const int col = n0 + wn + j * 16 + qi;
      if (col < Nmat) {
#pragma unroll
        for (int r = 0; r < 4; ++r)
          Cz[(size_t)(row + r) * ldc + col] = (bf16)acc[i][j][r];
      }
    }
  }
}

// ---------------- QKV split-K reduce + RoPE-Q (scale 1/8 folded) + KV extract ----------------
__global__ __launch_bounds__(256) void qkv_finish_k(const bf16* __restrict__ P,
                                                    size_t partStride,
                                                    const float* __restrict__ cs_tab,
                                                    const float* __restrict__ sn_tab,
                                                    bf16* __restrict__ Qb,
                                                    float* __restrict__ KVraw) {
  const int s = blockIdx.x, t = threadIdx.x;
  __shared__ float cs[64], sn[64];
  if (t < 64) { cs[t] = cs_tab[s * 64 + t]; sn[t] = sn_tab[s * 64 + t]; }
  __syncthreads();
  const bf16* r0 = P + (size_t)s * QKV_OUT;
  const bf16* r1 = r0 + partStride;
  for (int e = t; e < HIDDEN; e += 256) {
    const int d = e & 63;
    float x  = (float)r0[e] + (float)r1[e];
    float xp = (float)r0[e ^ 32] + (float)r1[e ^ 32];
    float rot = (d < 32) ? -xp : xp;
    Qb[(size_t)s * HIDDEN + e] = (bf16)((x * cs[d] + rot * sn[d]) * 0.125f);
  }
  if (t < 128)
    KVraw[s * 128 + t] = (float)r0[HIDDEN + t] + (float)r1[HIDDEN + t];
}

// ---------------- K (roped) and V -> MFMA-operand-ordered global layouts ----------------
__global__ __launch_bounds__(64) void kvprep_k(const float* __restrict__ KVraw,
                                               const float* __restrict__ cs_tab,
                                               const float* __restrict__ sn_tab,
                                               bf16* __restrict__ Kf,
                                               f16* __restrict__ Vf) {
  const int t16 = blockIdx.x, lane = threadIdx.x;
  const int qi = lane & 15, grp = lane >> 4;
  const int s = t16 * 16 + qi;
  const float* krow = KVraw + (size_t)s * 128;
  const float* cs = cs_tab + s * 64;
  const float* sn = sn_tab + s * 64;
#pragma unroll
  for (int half = 0; half < 2; ++half) {
    bf16x8 o;
    const int d0 = half * 32 + grp * 8;
#pragma unroll
    for (int j = 0; j < 8; ++j) {
      int d = d0 + j;
      float x = krow[d], xp = krow[d ^ 32];
      float rot = (d < 32) ? -xp : xp;
      o[j] = (bf16)(x * cs[d] + rot * sn[d]);
    }
    *(bf16x8*)&Kf[(t16 * 2 + half) * 512 + lane * 8] = o;
  }
#pragma unroll
  for (int tt = 0; tt < 4; ++tt) {
    f16x4 o;
#pragma unroll
    for (int j = 0; j < 4; ++j)
      o[j] = (f16)KVraw[(size_t)(t16 * 16 + grp * 4 + j) * 128 + 64 + tt * 16 + qi];
    *(f16x4*)&Vf[t16 * 1024 + tt * 256 + lane * 4] = o;
  }
}

// ---------------- causal MQA flash attention: 1 wave = (head, 32 q rows) ----------------
__global__ __launch_bounds__(64) void attn_k(const bf16* __restrict__ Qb,
                                             const bf16* __restrict__ Kf,
                                             const f16*  __restrict__ Vf,
                                             bf16* __restrict__ Ao) {
  __shared__ float fl[2 * 16 * 68];
  const int h = blockIdx.y;
  const int b32 = gridDim.x - 1 - blockIdx.x;   // big blocks first
  const int lane = threadIdx.x;
  const int qi = lane & 15, grp = lane >> 4;
  const int q0 = b32 * 32;
  const int lastT = b32 >> 1;

  bf16x8 qf[2][2];
#pragma unroll
  for (int qq = 0; qq < 2; ++qq) {
    const bf16* qb = Qb + (size_t)(q0 + qq * 16 + qi) * HIDDEN + h * 64 + grp * 8;
    qf[qq][0] = *(const bf16x8*)qb;
    qf[qq][1] = *(const bf16x8*)(qb + 32);
  }

  f32x4 o[2][4] = {};
  float l[2] = {0.f, 0.f};

  for (int kb = 0; kb <= lastT; ++kb) {
    const bf16* kfp = Kf + (size_t)kb * 4096 + lane * 8;
    bf16x8 kf[4][2];
#pragma unroll
    for (int kk = 0; kk < 4; ++kk) {
      kf[kk][0] = *(const bf16x8*)(kfp + kk * 1024);
      kf[kk][1] = *(const bf16x8*)(kfp + kk * 1024 + 512);
    }
    f32x4 s4[2][4];
#pragma unroll
    for (int qq = 0; qq < 2; ++qq)
#pragma unroll
      for (int kk = 0; kk < 4; ++kk) {
        f32x4 z = {};
        s4[qq][kk] = __builtin_amdgcn_mfma_f32_16x16x32_bf16(kf[kk][0], qf[qq][0], z, 0, 0, 0);
        s4[qq][kk] = __builtin_amdgcn_mfma_f32_16x16x32_bf16(kf[kk][1], qf[qq][1], s4[qq][kk], 0, 0, 0);
      }
    const f16* vfp = Vf + (size_t)kb * 4096 + lane * 4;
    f16x4 vf[4][4];
#pragma unroll
    for (int kk = 0; kk < 4; ++kk)
#pragma unroll
      for (int tt = 0; tt < 4; ++tt)
        vf[kk][tt] = *(const f16x4*)(vfp + kk * 1024 + tt * 256);

    if (kb == lastT) {
      const int dq = q0 - kb * 64 + qi;
#pragma unroll
      for (int qq = 0; qq < 2; ++qq)
#pragma unroll
        for (int kk = 0; kk < 4; ++kk)
#pragma unroll
          for (int r = 0; r < 4; ++r)
            if (kk * 16 + grp * 4 + r > dq + qq * 16) s4[qq][kk][r] = -1e30f;
    }
    f16x4 pf[2][4];
#pragma unroll
    for (int qq = 0; qq < 2; ++qq) {
      float ls = 0.f;
#pragma unroll
      for (int kk = 0; kk < 4; ++kk) {
        float p0 = __expf(s4[qq][kk][0]), p1 = __expf(s4[qq][kk][1]);
        float p2 = __expf(s4[qq][kk][2]), p3 = __expf(s4[qq][kk][3]);
        ls += (p0 + p1) + (p2 + p3);
        pf[qq][kk][0] = (f16)p0; pf[qq][kk][1] = (f16)p1;
        pf[qq][kk][2] = (f16)p2; pf[qq][kk][3] = (f16)p3;
      }
      l[qq] += ls;
    }
#pragma unroll
    for (int qq = 0; qq < 2; ++qq)
#pragma unroll
      for (int tt = 0; tt < 4; ++tt)
#pragma unroll
        for (int kk = 0; kk < 4; ++kk)
          o[qq][tt] = __builtin_amdgcn_mfma_f32_16x16x16f16(pf[qq][kk], vf[kk][tt], o[qq][tt], 0, 0, 0);
  }

#pragma unroll
  for (int qq = 0; qq < 2; ++qq) {
    float lq = l[qq];
    lq += __shfl_xor(lq, 16);
    lq += __shfl_xor(lq, 32);
    const float inv = 1.0f / lq;
    const float i0 = __shfl(inv, grp * 4 + 0);
    const float i1 = __shfl(inv, grp * 4 + 1);
    const float i2 = __shfl(inv, grp * 4 + 2);
    const float i3 = __shfl(inv, grp * 4 + 3);
    float* flq = fl + qq * 1088;
#pragma unroll
    for (int tt = 0; tt < 4; ++tt) {
      flq[(grp * 4 + 0) * 68 + tt * 16 + qi] = o[qq][tt][0] * i0;
      flq[(grp * 4 + 1) * 68 + tt * 16 + qi] = o[qq][tt][1] * i1;
      flq[(grp * 4 + 2) * 68 + tt * 16 + qi] = o[qq][tt][2] * i2;
      flq[(grp * 4 + 3) * 68 + tt * 16 + qi] = o[qq][tt][3] * i3;
    }
  }
  __syncthreads();
  const int row = lane >> 2, c0 = (lane & 3) * 16;
#pragma unroll
  for (int qq = 0; qq < 2; ++qq) {
    const float* flq = fl + qq * 1088;
    bf16x8 w0, w1;
#pragma unroll
    for (int j = 0; j < 8; ++j) {
      w0[j] = (bf16)flq[row * 68 + c0 + j];
      w1[j] = (bf16)flq[row * 68 + c0 + 8 + j];
    }
    bf16* ob = Ao + (size_t)(q0 + qq * 16 + row) * HIDDEN + h * 64 + c0;
    *(bf16x8*)ob = w0;
    *(bf16x8*)(ob + 8) = w1;
  }
}

// ---------------- dense split-K reduce -> fp32 out ----------------
__global__ void dense_finish_k(const bf16* __restrict__ P, size_t partStride,
                               float* __restrict__ out, int n8) {
  int i = blockIdx.x * blockDim.x + threadIdx.x;
  if (i >= n8) return;
  bf16x8 a = *(const bf16x8*)(P + (size_t)i * 8);
  bf16x8 b = *(const bf16x8*)(P + partStride + (size_t)i * 8);
  float4 o0, o1;
  o0.x = (float)a[0] + (float)b[0]; o0.y = (float)a[1] + (float)b[1];
  o0.z = (float)a[2] + (float)b[2]; o0.w = (float)a[3] + (float)b[3];
  o1.x = (float)a[4] + (float)b[4]; o1.y = (float)a[5] + (float)b[5];
  o1.z = (float)a[6] + (float)b[6]; o1.w = (float)a[7] + (float)b[7];
  ((float4*)out)[i * 2]     = o0;
  ((float4*)out)[i * 2 + 1] = o1;
}

// ---------------- launcher ----------------
extern "C" void kernel_launch(void* const* d_in, const int* in_sizes, int n_in,
                              void* d_out, int out_size, void* d_ws, size_t ws_size,
                              hipStream_t stream) {
  (void)in_sizes; (void)n_in; (void)out_size; (void)ws_size;
  const float* hs   = (const float*)d_in[0];
  const float* wqkv = (const float*)d_in[1];
  const float* wd   = (const float*)d_in[2];
  float* out = (float*)d_out;

  char* ws = (char*)d_ws;
  size_t off = 0;
  auto alloc = [&](size_t b) -> char* {
    char* p = ws + off;
    off += (b + 255) & ~(size_t)255;
    return p;
  };
  bf16* Xb     = (bf16*)alloc((size_t)SEQ * HIDDEN * 2);         // 18.6 MB
  bf16* Wqb    = (bf16*)alloc((size_t)QKV_OUT * HIDDEN * 2);     // 42.5 MB (reused as Ao)
  bf16* Wdb    = (bf16*)alloc((size_t)HIDDEN * HIDDEN * 2);      // 41.3 MB
  bf16* Part   = (bf16*)alloc((size_t)2 * SEQ * QKV_OUT * 2);    // 38.3 MB (both GEMMs' partials)
  bf16* Qb     = (bf16*)alloc((size_t)SEQ * HIDDEN * 2);         // 18.6 MB
  bf16* Kf     = (bf16*)alloc((size_t)(SEQ / 16) * 1024 * 2);
  f16*  Vf     = (f16*)alloc((size_t)(SEQ / 16) * 1024 * 2);
  float* KVraw  = (float*)alloc((size_t)SEQ * 128 * 4);
  float* cs_tab = (float*)alloc((size_t)SEQ * 64 * 4);
  float* sn_tab = (float*)alloc((size_t)SEQ * 64 * 4);
  bf16* Ao     = Wqb;   // Wqb dead after QKV GEMM

  {
    int n4 = SEQ * HIDDEN / 4;
    cvt_f32_bf16_k<<<(n4 + 255) / 256, 256, 0, stream>>>(hs, Xb, n4);
    n4 = QKV_OUT * HIDDEN / 4;
    cvt_f32_bf16_k<<<(n4 + 255) / 256, 256, 0, stream>>>(wqkv, Wqb, n4);
    n4 = HIDDEN * HIDDEN / 4;
    cvt_f32_bf16_k<<<(n4 + 255) / 256, 256, 0, stream>>>(wd, Wdb, n4);
  }
  tab_k<<<SEQ, 64, 0, stream>>>(cs_tab, sn_tab);

  const size_t strideQ = (size_t)SEQ * QKV_OUT;
  gemm_bt_splitk<<<dim3(SEQ / 128, (QKV_OUT + 127) / 128, 2), 256, 0, stream>>>(
      Xb, Wqb, Part, HIDDEN, QKV_OUT, QKV_OUT, strideQ);
  qkv_finish_k<<<SEQ, 256, 0, stream>>>(Part, strideQ, cs_tab, sn_tab, Qb, KVraw);
  kvprep_k<<<SEQ / 16, 64, 0, stream>>>(KVraw, cs_tab, sn_tab, Kf, Vf);
  attn_k<<<dim3(SEQ / 32, NHEAD), 64, 0, stream>>>(Qb, Kf, Vf, Ao);

  const size_t strideD = (size_t)SEQ * HIDDEN;
  gemm_bt_splitk<<<dim3(SEQ / 128, (HIDDEN + 127) / 128, 2), 256, 0, stream>>>(
      Ao, Wdb, Part, HIDDEN, HIDDEN, HIDDEN, strideD);
  dense_finish_k<<<(SEQ * HIDDEN / 8 + 255) / 256, 256, 0, stream>>>(
      Part, strideD, out, SEQ * HIDDEN / 8);
}